// Round 18
// baseline (674.547 us; speedup 1.0000x reference)
//
#include <hip/hip_runtime.h>
#include <cstddef>

#define SLOPE_F (11.0f / 48.0f)

static const int NN = 50000;     // nodes
static const int EE = 1600000;   // edges per timestep
static const int D  = 256;
static const int NCH = 196;      // scan chunks = ceil(NN/256)
static const int GB  = 391;      // gemm blocks (128-row) = ceil(NN/128)
static const int ABLK = 12500;   // agg dst-blocks = ceil(NN/4)

typedef __attribute__((ext_vector_type(8))) short short8;
typedef __attribute__((ext_vector_type(4))) float f32x4;
typedef __attribute__((ext_vector_type(2))) float f32x2;

__device__ __forceinline__ ushort f2bf(float f) {
    unsigned u = __float_as_uint(f);
    unsigned r = (u + 0x7fffu + ((u >> 16) & 1u)) >> 16;
    return (ushort)r;
}
__device__ __forceinline__ float bf2f(ushort u) {
    return __uint_as_float(((unsigned)u) << 16);
}

// f32 -> fp8 e4m3fn (RNE on normals, clamp to +-448, subnormals handled)
__device__ __forceinline__ unsigned enc8(float x) {
    unsigned ux = __float_as_uint(x);
    unsigned sign = (ux >> 31) << 7;
    float ax = __uint_as_float(ux & 0x7fffffffu);
    if (!(ax < 448.f)) return sign | 0x7E;
    if (ax < 0.015625f) {
        int m = (int)(ax * 512.f + 0.5f);
        if (m > 7) return sign | 0x08;
        return sign | m;
    }
    unsigned u = __float_as_uint(ax);
    u += 0x7FFFFu + ((u >> 20) & 1u);
    int e = (int)((u >> 23) & 255) - 127 + 7;
    if (e > 15) return sign | 0x7E;
    return sign | (e << 3) | ((u >> 20) & 7);
}

// ---------------- prep + dst histogram (8-replica, rank capture) ----------------
__global__ __launch_bounds__(256) void prephist_kernel(
        const float* __restrict__ Wz0, const float* __restrict__ Uz0,
        const float* __restrict__ Wr0, const float* __restrict__ Ur0,
        const float* __restrict__ Wh0, const float* __restrict__ Uh0,
        const float* __restrict__ Wz1, const float* __restrict__ Uz1,
        const float* __restrict__ Wr1, const float* __restrict__ Ur1,
        const float* __restrict__ Wh1, const float* __restrict__ Uh1,
        const float* __restrict__ W1,
        ushort* __restrict__ WB, ushort* __restrict__ BtW1,
        const int* __restrict__ dst, int* __restrict__ D8,
        ushort* __restrict__ rank) {
    int b = blockIdx.x;
    int tid = threadIdx.x;
    if (b >= 144) {
        int e = (b - 144) * 256 + tid;
        if (e < EE) {
            int d = dst[e];
            rank[e] = (ushort)atomicAdd(&D8[(e & 7) * NN + d], 1);
        }
        return;
    }
    __shared__ float lt[64][65];
    if (b < 128) {
        int mat = b >> 4;
        int tr = (b >> 2) & 3, tc = b & 3;
        const float* P = nullptr; const float* S = nullptr;
        switch (mat) {
            case 0: P = Wz0; S = Uz0; break;
            case 1: P = Wr0; S = Ur0; break;
            case 2: P = Wh0; break;
            case 3: P = Uh0; break;
            case 4: P = Wz1; S = Uz1; break;
            case 5: P = Wr1; S = Ur1; break;
            case 6: P = Wh1; break;
            default: P = Uh1; break;
        }
#pragma unroll
        for (int r0 = 0; r0 < 64; r0 += 4) {
            int r = r0 + (tid >> 6);
            int c = tid & 63;
            int row = tr * 64 + r, col = tc * 64 + c;
            float v = P[row * 256 + col];
            if (S) v += S[row * 256 + col];
            lt[r][c] = v;
        }
        __syncthreads();
#pragma unroll
        for (int c0 = 0; c0 < 64; c0 += 4) {
            int c = c0 + (tid >> 6);
            int r = tid & 63;
            WB[(size_t)mat * 65536 + (size_t)(tc * 64 + c) * 256 + tr * 64 + r] =
                f2bf(lt[r][c]);
        }
    } else {
        int t = b - 128;
        int tr = (t >> 2) & 3, tc = t & 3;
#pragma unroll
        for (int r0 = 0; r0 < 64; r0 += 4) {
            int r = r0 + (tid >> 6);
            int c = tid & 63;
            lt[r][c] = W1[(tr * 64 + r) * 256 + tc * 64 + c];
        }
        __syncthreads();
#pragma unroll
        for (int c0 = 0; c0 < 64; c0 += 4) {
            int c = c0 + (tid >> 6);
            int r = tid & 63;
            BtW1[(size_t)(tc * 64 + c) * 256 + tr * 64 + r] = f2bf(lt[r][c]);
        }
    }
}

// ---------------- GRU (512 blocks, 1 col each) + chunk-scan (blocks 512..707) ----
__global__ __launch_bounds__(256) void gruscan_kernel(
        const ushort* __restrict__ WB,
        const float* __restrict__ bz0, const float* __restrict__ br0,
        const float* __restrict__ bh0, const float* __restrict__ Q00,
        const float* __restrict__ bz1, const float* __restrict__ br1,
        const float* __restrict__ bh1, const float* __restrict__ Q01,
        ushort* __restrict__ Bt,
        const int* __restrict__ D8, int* __restrict__ rs, int* __restrict__ base8,
        int* __restrict__ bsum, int* __restrict__ boff, int* __restrict__ done) {
    int tid = threadIdx.x;
    if (blockIdx.x >= 512) {
        __shared__ int wsum[4];
        __shared__ int lastflag;
        int blk = blockIdx.x - 512;
        int i = blk * 256 + tid;
        int lane = tid & 63, wv = tid >> 6;
        int c[8];
        int v = 0;
#pragma unroll
        for (int r = 0; r < 8; ++r) {
            c[r] = (i < NN) ? D8[r * NN + i] : 0;
            v += c[r];
        }
        int x = v;
#pragma unroll
        for (int off = 1; off < 64; off <<= 1) {
            int t = __shfl_up(x, off, 64);
            if (lane >= off) x += t;
        }
        if (lane == 63) wsum[wv] = x;
        __syncthreads();
        if (tid == 0) {
            int s = 0;
#pragma unroll
            for (int q = 0; q < 4; ++q) { int t = wsum[q]; wsum[q] = s; s += t; }
            bsum[blk] = s;
        }
        __syncthreads();
        if (i < NN) {
            int p = wsum[wv] + x - v;
            rs[i] = p;
            int b = p;
            int4 b0, b1;
            b0.x = b; b += c[0]; b0.y = b; b += c[1];
            b0.z = b; b += c[2]; b0.w = b; b += c[3];
            b1.x = b; b += c[4]; b1.y = b; b += c[5];
            b1.z = b; b += c[6]; b1.w = b;
            *(int4*)&base8[8 * i]     = b0;
            *(int4*)&base8[8 * i + 4] = b1;
        }
        __threadfence();
        if (tid == 0) lastflag = (atomicAdd(done, 1) == NCH - 1);
        __syncthreads();
        if (lastflag) {
            __threadfence();
            int bv = (tid < NCH) ? bsum[tid] : 0;
            int bx = bv;
#pragma unroll
            for (int off = 1; off < 64; off <<= 1) {
                int t = __shfl_up(bx, off, 64);
                if (lane >= off) bx += t;
            }
            if (lane == 63) wsum[wv] = bx;
            __syncthreads();
            if (tid == 0) {
                int s = 0;
#pragma unroll
                for (int q = 0; q < 4; ++q) { int t = wsum[q]; wsum[q] = s; s += t; }
            }
            __syncthreads();
            if (tid < NCH) boff[tid] = wsum[wv] + bx - bv;
        }
        return;
    }
    __shared__ float qs[256];
    __shared__ float rqs[256];
    int layer = blockIdx.x >> 8;
    int j = blockIdx.x & 255;
    int i = tid;
    const ushort* Mz = WB + ((size_t)layer * 4 + 0) * 65536;
    const ushort* Mr = WB + ((size_t)layer * 4 + 1) * 65536;
    const ushort* Wh = WB + ((size_t)layer * 4 + 2) * 65536;
    const ushort* Uh = WB + ((size_t)layer * 4 + 3) * 65536;
    const float* bz = layer ? bz1 : bz0;
    const float* br = layer ? br1 : br0;
    const float* bh = layer ? bh1 : bh0;
    const float* Q0 = layer ? Q01 : Q00;

    float bzv = bz[i * 256 + j];
    float brv = br[i * 256 + j];
    float bhv = bh[i * 256 + j];

    qs[i] = Q0[i * 256 + j];
    __syncthreads();

    for (int step = 0; step < 6; ++step) {
        float az = 0.f, ar = 0.f, ah = 0.f;
#pragma unroll 8
        for (int k = 0; k < 256; ++k) {
            float q = qs[k];
            az += bf2f(Mz[k * 256 + i]) * q;
            ar += bf2f(Mr[k * 256 + i]) * q;
            ah += bf2f(Wh[k * 256 + i]) * q;
        }
        float zz = 1.f / (1.f + expf(-(az + bzv)));
        float rr = 1.f / (1.f + expf(-(ar + brv)));
        float qo = qs[i];
        rqs[i] = rr * qo;
        __syncthreads();
        float bu = 0.f;
#pragma unroll 8
        for (int k = 0; k < 256; ++k)
            bu += bf2f(Uh[k * 256 + i]) * rqs[k];
        float h = tanhf(ah + bu + bhv);
        float qn = (1.f - zz) * qo + zz * h;
        __syncthreads();
        qs[i] = qn;
        __syncthreads();
    }
    Bt[(size_t)layer * 65536 + (size_t)j * 256 + i] = f2bf(qs[i]);
}

// ---------------- MFMA GEMM body (fp8-permuted output) ----------------
template <int ASRC>
__device__ __forceinline__ void gemm_body(int bid, int tid,
                                          const ushort* __restrict__ A,
                                          const float* __restrict__ Af,
                                          const ushort* __restrict__ Bt,
                                          unsigned char* __restrict__ C8, int M) {
    int w = tid >> 6, l = tid & 63;
    int lr = l & 15;
    int lk = l >> 4;
    int row0 = bid * 128 + w * 32;
    int ra = row0 + lr;      if (ra > M - 1) ra = M - 1;
    int rb = row0 + 16 + lr; if (rb > M - 1) rb = M - 1;
    const ushort* Ap0  = A  + (size_t)ra * 256 + lk * 8;
    const ushort* Ap1  = A  + (size_t)rb * 256 + lk * 8;
    const float*  Apf0 = Af + (size_t)ra * 256 + lk * 8;
    const float*  Apf1 = Af + (size_t)rb * 256 + lk * 8;
    const ushort* Bp   = Bt + (size_t)lr * 256 + lk * 8;

    f32x4 acc0[16] = {};
    f32x4 acc1[16] = {};
#pragma unroll
    for (int kc = 0; kc < 8; ++kc) {
        short8 a0, a1;
        if (ASRC == 0) {
            a0 = *(const short8*)(Ap0 + kc * 32);
            a1 = *(const short8*)(Ap1 + kc * 32);
        } else {
            float4 f0 = *(const float4*)(Apf0 + kc * 32);
            float4 f1 = *(const float4*)(Apf0 + kc * 32 + 4);
            float4 g0 = *(const float4*)(Apf1 + kc * 32);
            float4 g1 = *(const float4*)(Apf1 + kc * 32 + 4);
            a0[0] = (short)f2bf(f0.x); a0[1] = (short)f2bf(f0.y);
            a0[2] = (short)f2bf(f0.z); a0[3] = (short)f2bf(f0.w);
            a0[4] = (short)f2bf(f1.x); a0[5] = (short)f2bf(f1.y);
            a0[6] = (short)f2bf(f1.z); a0[7] = (short)f2bf(f1.w);
            a1[0] = (short)f2bf(g0.x); a1[1] = (short)f2bf(g0.y);
            a1[2] = (short)f2bf(g0.z); a1[3] = (short)f2bf(g0.w);
            a1[4] = (short)f2bf(g1.x); a1[5] = (short)f2bf(g1.y);
            a1[6] = (short)f2bf(g1.z); a1[7] = (short)f2bf(g1.w);
        }
#pragma unroll
        for (int nb = 0; nb < 16; ++nb) {
            short8 bf = *(const short8*)(Bp + (size_t)nb * 4096 + kc * 32);
            acc0[nb] = __builtin_amdgcn_mfma_f32_16x16x32_bf16(a0, bf, acc0[nb], 0, 0, 0);
            acc1[nb] = __builtin_amdgcn_mfma_f32_16x16x32_bf16(a1, bf, acc1[nb], 0, 0, 0);
        }
    }

    int ro = lk * 4;
#pragma unroll
    for (int q = 0; q < 4; ++q) {
        unsigned w0[4], w1[4];
#pragma unroll
        for (int t = 0; t < 4; ++t) {
            unsigned x0 = 0, x1 = 0;
#pragma unroll
            for (int u = 0; u < 4; ++u) {
                x0 |= enc8(acc0[t * 4 + u][q]) << (8 * u);
                x1 |= enc8(acc1[t * 4 + u][q]) << (8 * u);
            }
            w0[t] = x0; w1[t] = x1;
        }
        int g0 = row0 + ro + q;
        if (g0 < M)
            *(uint4*)&C8[(size_t)g0 * 256 + lr * 16] = make_uint4(w0[0], w0[1], w0[2], w0[3]);
        int g1 = row0 + 16 + ro + q;
        if (g1 < M)
            *(uint4*)&C8[(size_t)g1 * 256 + lr * 16] = make_uint4(w1[0], w1[1], w1[2], w1[3]);
    }
}

__global__ __launch_bounds__(256) void gemm_mfma(const ushort* __restrict__ A,
                                                 const ushort* __restrict__ Bt,
                                                 unsigned char* __restrict__ C8, int M) {
    gemm_body<0>(blockIdx.x, threadIdx.x, A, nullptr, Bt, C8, M);
}

// ---------------- merged: gemm0 (fp8 out) + atomic-free rank scatter (4B entries) ----
__global__ __launch_bounds__(256) void gemsca_kernel(const float* __restrict__ Af,
                                                     const ushort* __restrict__ Bt,
                                                     unsigned char* __restrict__ C8, int M,
                                                     const int* __restrict__ src,
                                                     const int* __restrict__ dst,
                                                     const float* __restrict__ val,
                                                     const int* __restrict__ base8,
                                                     const int* __restrict__ boff,
                                                     const ushort* __restrict__ rank,
                                                     unsigned* __restrict__ csr) {
    if (blockIdx.x < GB) {
        gemm_body<1>(blockIdx.x, threadIdx.x, nullptr, Af, Bt, C8, M);
        return;
    }
    int e = (blockIdx.x - GB) * 256 + threadIdx.x;
    if (e < EE) {
        int d = dst[e];
        int p = base8[8 * d + (e & 7)] + boff[d >> 8] + (int)rank[e];
        unsigned pk = (unsigned)src[e] | ((unsigned)f2bf(val[e]) << 16);
        __builtin_nontemporal_store(pk, &csr[p]);
    }
}

// ---------------- fused gemm2 + MLP head ----------------
__global__ __launch_bounds__(256) void gemm2_kernel(const ushort* __restrict__ A,
                                                    const ushort* __restrict__ Bt,
                                                    const float* __restrict__ bias,
                                                    const float* __restrict__ W2,
                                                    const float* __restrict__ b2,
                                                    float* __restrict__ out, int M) {
    __shared__ ushort Hl[128 * 264];
    int tid = threadIdx.x;
    int w = tid >> 6, l = tid & 63;
    int lr = l & 15;
    int lk = l >> 4;
    int row0 = blockIdx.x * 128 + w * 32;
    int ra = row0 + lr;      if (ra > M - 1) ra = M - 1;
    int rb = row0 + 16 + lr; if (rb > M - 1) rb = M - 1;
    const ushort* Ap0 = A + (size_t)ra * 256 + lk * 8;
    const ushort* Ap1 = A + (size_t)rb * 256 + lk * 8;
    const ushort* Bp  = Bt + (size_t)lr * 256 + lk * 8;

    f32x4 acc0[16] = {};
    f32x4 acc1[16] = {};
#pragma unroll
    for (int kc = 0; kc < 8; ++kc) {
        short8 a0 = *(const short8*)(Ap0 + kc * 32);
        short8 a1 = *(const short8*)(Ap1 + kc * 32);
#pragma unroll
        for (int nb = 0; nb < 16; ++nb) {
            short8 bf = *(const short8*)(Bp + (size_t)nb * 4096 + kc * 32);
            acc0[nb] = __builtin_amdgcn_mfma_f32_16x16x32_bf16(a0, bf, acc0[nb], 0, 0, 0);
            acc1[nb] = __builtin_amdgcn_mfma_f32_16x16x32_bf16(a1, bf, acc1[nb], 0, 0, 0);
        }
    }

    int ro = lk * 4;
    int lrow0 = w * 32;
#pragma unroll
    for (int nb = 0; nb < 16; ++nb) {
        int gc = nb * 16 + lr;
        float bb = bias[gc];
#pragma unroll
        for (int q = 0; q < 4; ++q) {
            Hl[(lrow0 + ro + q) * 264 + gc]      = f2bf(fmaxf(acc0[nb][q] + bb, 0.f));
            Hl[(lrow0 + 16 + ro + q) * 264 + gc] = f2bf(fmaxf(acc1[nb][q] + bb, 0.f));
        }
    }
    __syncthreads();

    int c = tid & 15;
    float b2v = b2[c];
#pragma unroll
    for (int it = 0; it < 8; ++it) {
        int r = it * 16 + (tid >> 4);
        int g = blockIdx.x * 128 + r;
        const ushort* hp = &Hl[r * 264];
        float acc2 = b2v;
        for (int k8 = 0; k8 < 32; ++k8) {
            short8 h8 = *(const short8*)(hp + k8 * 8);
#pragma unroll
            for (int u = 0; u < 8; ++u)
                acc2 += bf2f((ushort)h8[u]) * W2[(k8 * 8 + u) * 16 + c];
        }
        float m = acc2;
#pragma unroll
        for (int off = 1; off < 16; off <<= 1)
            m = fmaxf(m, __shfl_xor(m, off, 16));
        float ex = expf(acc2 - m);
        float s = ex;
#pragma unroll
        for (int off = 1; off < 16; off <<= 1)
            s += __shfl_xor(s, off, 16);
        if (g < M) out[(size_t)g * 16 + c] = acc2 - m - logf(s);
    }
}

// ---------------- column-sliced pull aggregation (fp8 gather, L2-resident slices) ----
// grid = 4 slices x ABLK; wave = one dst x one 64-byte slice.
// 16 lanes cover the slice (4 fp8 each); 4 lane-groups process 4 edges in parallel.
__global__ __launch_bounds__(256) void agg_csr_kernel(const unsigned char* __restrict__ XW,
                                                      const unsigned* __restrict__ csr,
                                                      const int* __restrict__ rs,
                                                      const int* __restrict__ boff,
                                                      ushort* __restrict__ out) {
    int bid = blockIdx.x;
    int slice = bid / ABLK;          // 0..3
    int dblk = bid - slice * ABLK;
    int d = dblk * 4 + (threadIdx.x >> 6);
    if (d >= NN) return;
    int l = threadIdx.x & 63;
    int h = l >> 4;          // edge group 0..3
    int il = l & 15;         // 4 fp8 at slice*64 + il*4
    const unsigned char* XWs = XW + slice * 64 + il * 4;
    int beg = rs[d] + boff[d >> 8];
    int end = (d + 1 < NN) ? (rs[d + 1] + boff[(d + 1) >> 8]) : EE;
    float a0 = 0.f, a1 = 0.f, a2 = 0.f, a3 = 0.f;
    int i = beg + h;
    for (; i + 12 < end; i += 16) {
        unsigned e[4];
        unsigned x[4];
#pragma unroll
        for (int u = 0; u < 4; ++u) e[u] = csr[i + 4 * u];
#pragma unroll
        for (int u = 0; u < 4; ++u)
            x[u] = *(const unsigned*)(XWs + (size_t)(e[u] & 0xffffu) * 256);
#pragma unroll
        for (int u = 0; u < 4; ++u) {
            float v = bf2f((ushort)(e[u] >> 16));
            f32x2 p0 = __builtin_amdgcn_cvt_pk_f32_fp8(x[u], false);
            f32x2 p1 = __builtin_amdgcn_cvt_pk_f32_fp8(x[u], true);
            a0 += v * p0.x; a1 += v * p0.y; a2 += v * p1.x; a3 += v * p1.y;
        }
    }
    for (; i < end; i += 4) {
        unsigned e0 = csr[i];
        float v = bf2f((ushort)(e0 >> 16));
        unsigned x0 = *(const unsigned*)(XWs + (size_t)(e0 & 0xffffu) * 256);
        f32x2 p0 = __builtin_amdgcn_cvt_pk_f32_fp8(x0, false);
        f32x2 p1 = __builtin_amdgcn_cvt_pk_f32_fp8(x0, true);
        a0 += v * p0.x; a1 += v * p0.y; a2 += v * p1.x; a3 += v * p1.y;
    }
    // combine the 4 edge groups (lanes l, l^16, l^32, l^48)
    a0 += __shfl_xor(a0, 16); a0 += __shfl_xor(a0, 32);
    a1 += __shfl_xor(a1, 16); a1 += __shfl_xor(a1, 32);
    a2 += __shfl_xor(a2, 16); a2 += __shfl_xor(a2, 32);
    a3 += __shfl_xor(a3, 16); a3 += __shfl_xor(a3, 32);
    if (h == 0) {
        float r[4] = {a0, a1, a2, a3};
#pragma unroll
        for (int u = 0; u < 4; ++u) {
            int p = slice * 64 + il * 4 + u;
            int c = ((p & 15) << 4) | (p >> 4);
            float v = r[u];
            v = (v >= 0.f) ? v : SLOPE_F * v;
            out[(size_t)d * D + c] = f2bf(v);
        }
    }
}

extern "C" void kernel_launch(void* const* d_in, const int* in_sizes, int n_in,
                              void* d_out, int out_size, void* d_ws, size_t ws_size,
                              hipStream_t stream) {
    const float* node_feats = (const float*)d_in[0];
    const float* edge_val   = (const float*)d_in[1];
    const float* l0_Wz = (const float*)d_in[2];
    const float* l0_Uz = (const float*)d_in[3];
    const float* l0_bz = (const float*)d_in[4];
    const float* l0_Wr = (const float*)d_in[5];
    const float* l0_Ur = (const float*)d_in[6];
    const float* l0_br = (const float*)d_in[7];
    const float* l0_Wh = (const float*)d_in[8];
    const float* l0_Uh = (const float*)d_in[9];
    const float* l0_bh = (const float*)d_in[10];
    const float* l0_Q0 = (const float*)d_in[11];
    const float* l1_Wz = (const float*)d_in[12];
    const float* l1_Uz = (const float*)d_in[13];
    const float* l1_bz = (const float*)d_in[14];
    const float* l1_Wr = (const float*)d_in[15];
    const float* l1_Ur = (const float*)d_in[16];
    const float* l1_br = (const float*)d_in[17];
    const float* l1_Wh = (const float*)d_in[18];
    const float* l1_Uh = (const float*)d_in[19];
    const float* l1_bh = (const float*)d_in[20];
    const float* l1_Q0 = (const float*)d_in[21];
    const float* W1 = (const float*)d_in[22];
    const float* b1 = (const float*)d_in[23];
    const float* W2 = (const float*)d_in[24];
    const float* b2 = (const float*)d_in[25];
    const int* e_src = (const int*)d_in[26];
    const int* e_dst = (const int*)d_in[27];
    float* out = (float*)d_out;

    // workspace layout (16B-aligned sections)
    const size_t BIG = (size_t)NN * D;   // 12.8M elements
    unsigned char* XW8 = (unsigned char*)d_ws;   // fp8 GEMM out (12.8 MB)
    ushort* H   = (ushort*)(XW8 + BIG);          // bf16 activations (h1/h2)
    ushort* Bt  = H + BIG;                       // 3 x 65536 bf16 (Qt0, Qt1, W1T)
    ushort* WB  = Bt + 3 * 65536;                // 8 mats x 65536 bf16 (transposed)
    unsigned* csr = (unsigned*)(WB + 8 * 65536); // EE (4B entries)
    int*    D8  = (int*)(csr + EE);              // 8*NN (histogram replicas)
    int*    done = D8 + 8 * NN;                  // 1 (+3 pad)
    int*    rs  = done + 4;                      // NN
    int*    base8 = rs + NN;                     // 8*NN
    int*    bsum = base8 + 8 * NN;               // 200
    int*    boff = bsum + 200;                   // 200
    ushort* rank = (ushort*)(boff + 200);        // EE

    // --- only timestep 5 contributes to the output ---
    const float* feats5 = node_feats + (size_t)5 * BIG;
    const int*   src5   = e_src + (size_t)5 * EE;
    const int*   dst5   = e_dst + (size_t)5 * EE;
    const float* val5   = edge_val + (size_t)5 * EE;

    // zero histogram replicas + done
    hipMemsetAsync(D8, 0, (8 * NN + 1) * sizeof(int), stream);

    // --- prep (144 blocks) + histogram w/ rank capture ---
    const int histblocks = (EE + 255) / 256;
    prephist_kernel<<<144 + histblocks, 256, 0, stream>>>(
        l0_Wz, l0_Uz, l0_Wr, l0_Ur, l0_Wh, l0_Uh,
        l1_Wz, l1_Uz, l1_Wr, l1_Ur, l1_Wh, l1_Uh,
        W1, WB, Bt + 2 * 65536, dst5, D8, rank);

    // --- GRU (512 blocks) + hierarchical scan over replicas (196 blocks) ---
    gruscan_kernel<<<512 + NCH, 256, 0, stream>>>(WB, l0_bz, l0_br, l0_bh, l0_Q0,
                                                  l1_bz, l1_br, l1_bh, l1_Q0, Bt,
                                                  D8, rs, base8, bsum, boff, done);

    // --- gemm0 (A = fp32 feats, B = Qt0, out fp8-permuted) + rank scatter ---
    gemsca_kernel<<<GB + histblocks, 256, 0, stream>>>(feats5, Bt + 0 * 65536, XW8, NN,
                                                       src5, dst5, val5, base8, boff,
                                                       rank, csr);

    // agg0: column-sliced fp8 gather -> bf16 h1
    agg_csr_kernel<<<4 * ABLK, 256, 0, stream>>>(XW8, csr, rs, boff, H);

    // gemm1: h1 @ Qt1 -> fp8-permuted
    gemm_mfma<<<GB, 256, 0, stream>>>(H, Bt + 1 * 65536, XW8, NN);

    // agg1: column-sliced fp8 gather -> bf16 h2
    agg_csr_kernel<<<4 * ABLK, 256, 0, stream>>>(XW8, csr, rs, boff, H);

    // gemm2 + bias/relu + MLP head + log_softmax, fused
    gemm2_kernel<<<GB, 256, 0, stream>>>(H, Bt + 2 * 65536, b1, W2, b2, out, NN);
}

// Round 19
// 571.329 us; speedup vs baseline: 1.1807x; 1.1807x over previous
//
#include <hip/hip_runtime.h>
#include <cstddef>

#define SLOPE_F (11.0f / 48.0f)

static const int NN = 50000;     // nodes
static const int EE = 1600000;   // edges per timestep
static const int D  = 256;
static const int NCH = 196;      // scan chunks = ceil(NN/256)
static const int GB  = 391;      // gemm blocks (128-row) = ceil(NN/128)

typedef __attribute__((ext_vector_type(8))) short short8;
typedef __attribute__((ext_vector_type(4))) float f32x4;
typedef __attribute__((ext_vector_type(2))) float f32x2;

__device__ __forceinline__ ushort f2bf(float f) {
    unsigned u = __float_as_uint(f);
    unsigned r = (u + 0x7fffu + ((u >> 16) & 1u)) >> 16;
    return (ushort)r;
}
__device__ __forceinline__ float bf2f(ushort u) {
    return __uint_as_float(((unsigned)u) << 16);
}

// f32 -> fp8 e4m3fn (RNE on normals, clamp to +-448, subnormals handled)
__device__ __forceinline__ unsigned enc8(float x) {
    unsigned ux = __float_as_uint(x);
    unsigned sign = (ux >> 31) << 7;
    float ax = __uint_as_float(ux & 0x7fffffffu);
    if (!(ax < 448.f)) return sign | 0x7E;
    if (ax < 0.015625f) {
        int m = (int)(ax * 512.f + 0.5f);
        if (m > 7) return sign | 0x08;
        return sign | m;
    }
    unsigned u = __float_as_uint(ax);
    u += 0x7FFFFu + ((u >> 20) & 1u);
    int e = (int)((u >> 23) & 255) - 127 + 7;
    if (e > 15) return sign | 0x7E;
    return sign | (e << 3) | ((u >> 20) & 7);
}

// ---------------- prep + dst histogram (8-replica, rank capture) ----------------
__global__ __launch_bounds__(256) void prephist_kernel(
        const float* __restrict__ Wz0, const float* __restrict__ Uz0,
        const float* __restrict__ Wr0, const float* __restrict__ Ur0,
        const float* __restrict__ Wh0, const float* __restrict__ Uh0,
        const float* __restrict__ Wz1, const float* __restrict__ Uz1,
        const float* __restrict__ Wr1, const float* __restrict__ Ur1,
        const float* __restrict__ Wh1, const float* __restrict__ Uh1,
        const float* __restrict__ W1,
        ushort* __restrict__ WB, ushort* __restrict__ BtW1,
        const int* __restrict__ dst, int* __restrict__ D8,
        ushort* __restrict__ rank) {
    int b = blockIdx.x;
    int tid = threadIdx.x;
    if (b >= 144) {
        int e = (b - 144) * 256 + tid;
        if (e < EE) {
            int d = dst[e];
            rank[e] = (ushort)atomicAdd(&D8[(e & 7) * NN + d], 1);
        }
        return;
    }
    __shared__ float lt[64][65];
    if (b < 128) {
        int mat = b >> 4;
        int tr = (b >> 2) & 3, tc = b & 3;
        const float* P = nullptr; const float* S = nullptr;
        switch (mat) {
            case 0: P = Wz0; S = Uz0; break;
            case 1: P = Wr0; S = Ur0; break;
            case 2: P = Wh0; break;
            case 3: P = Uh0; break;
            case 4: P = Wz1; S = Uz1; break;
            case 5: P = Wr1; S = Ur1; break;
            case 6: P = Wh1; break;
            default: P = Uh1; break;
        }
#pragma unroll
        for (int r0 = 0; r0 < 64; r0 += 4) {
            int r = r0 + (tid >> 6);
            int c = tid & 63;
            int row = tr * 64 + r, col = tc * 64 + c;
            float v = P[row * 256 + col];
            if (S) v += S[row * 256 + col];
            lt[r][c] = v;
        }
        __syncthreads();
#pragma unroll
        for (int c0 = 0; c0 < 64; c0 += 4) {
            int c = c0 + (tid >> 6);
            int r = tid & 63;
            WB[(size_t)mat * 65536 + (size_t)(tc * 64 + c) * 256 + tr * 64 + r] =
                f2bf(lt[r][c]);
        }
    } else {
        int t = b - 128;
        int tr = (t >> 2) & 3, tc = t & 3;
#pragma unroll
        for (int r0 = 0; r0 < 64; r0 += 4) {
            int r = r0 + (tid >> 6);
            int c = tid & 63;
            lt[r][c] = W1[(tr * 64 + r) * 256 + tc * 64 + c];
        }
        __syncthreads();
#pragma unroll
        for (int c0 = 0; c0 < 64; c0 += 4) {
            int c = c0 + (tid >> 6);
            int r = tid & 63;
            BtW1[(size_t)(tc * 64 + c) * 256 + tr * 64 + r] = f2bf(lt[r][c]);
        }
    }
}

// ---------------- GRU (512 blocks, 1 col each) + chunk-scan (blocks 512..707) ----
__global__ __launch_bounds__(256) void gruscan_kernel(
        const ushort* __restrict__ WB,
        const float* __restrict__ bz0, const float* __restrict__ br0,
        const float* __restrict__ bh0, const float* __restrict__ Q00,
        const float* __restrict__ bz1, const float* __restrict__ br1,
        const float* __restrict__ bh1, const float* __restrict__ Q01,
        ushort* __restrict__ Bt,
        const int* __restrict__ D8, int* __restrict__ rs, int* __restrict__ base8,
        int* __restrict__ bsum, int* __restrict__ boff, int* __restrict__ done) {
    int tid = threadIdx.x;
    if (blockIdx.x >= 512) {
        __shared__ int wsum[4];
        __shared__ int lastflag;
        int blk = blockIdx.x - 512;
        int i = blk * 256 + tid;
        int lane = tid & 63, wv = tid >> 6;
        int c[8];
        int v = 0;
#pragma unroll
        for (int r = 0; r < 8; ++r) {
            c[r] = (i < NN) ? D8[r * NN + i] : 0;
            v += c[r];
        }
        int x = v;
#pragma unroll
        for (int off = 1; off < 64; off <<= 1) {
            int t = __shfl_up(x, off, 64);
            if (lane >= off) x += t;
        }
        if (lane == 63) wsum[wv] = x;
        __syncthreads();
        if (tid == 0) {
            int s = 0;
#pragma unroll
            for (int q = 0; q < 4; ++q) { int t = wsum[q]; wsum[q] = s; s += t; }
            bsum[blk] = s;
        }
        __syncthreads();
        if (i < NN) {
            int p = wsum[wv] + x - v;
            rs[i] = p;
            int b = p;
            int4 b0, b1;
            b0.x = b; b += c[0]; b0.y = b; b += c[1];
            b0.z = b; b += c[2]; b0.w = b; b += c[3];
            b1.x = b; b += c[4]; b1.y = b; b += c[5];
            b1.z = b; b += c[6]; b1.w = b;
            *(int4*)&base8[8 * i]     = b0;
            *(int4*)&base8[8 * i + 4] = b1;
        }
        __threadfence();
        if (tid == 0) lastflag = (atomicAdd(done, 1) == NCH - 1);
        __syncthreads();
        if (lastflag) {
            __threadfence();
            int bv = (tid < NCH) ? bsum[tid] : 0;
            int bx = bv;
#pragma unroll
            for (int off = 1; off < 64; off <<= 1) {
                int t = __shfl_up(bx, off, 64);
                if (lane >= off) bx += t;
            }
            if (lane == 63) wsum[wv] = bx;
            __syncthreads();
            if (tid == 0) {
                int s = 0;
#pragma unroll
                for (int q = 0; q < 4; ++q) { int t = wsum[q]; wsum[q] = s; s += t; }
            }
            __syncthreads();
            if (tid < NCH) boff[tid] = wsum[wv] + bx - bv;
        }
        return;
    }
    __shared__ float qs[256];
    __shared__ float rqs[256];
    int layer = blockIdx.x >> 8;
    int j = blockIdx.x & 255;
    int i = tid;
    const ushort* Mz = WB + ((size_t)layer * 4 + 0) * 65536;
    const ushort* Mr = WB + ((size_t)layer * 4 + 1) * 65536;
    const ushort* Wh = WB + ((size_t)layer * 4 + 2) * 65536;
    const ushort* Uh = WB + ((size_t)layer * 4 + 3) * 65536;
    const float* bz = layer ? bz1 : bz0;
    const float* br = layer ? br1 : br0;
    const float* bh = layer ? bh1 : bh0;
    const float* Q0 = layer ? Q01 : Q00;

    float bzv = bz[i * 256 + j];
    float brv = br[i * 256 + j];
    float bhv = bh[i * 256 + j];

    qs[i] = Q0[i * 256 + j];
    __syncthreads();

    for (int step = 0; step < 6; ++step) {
        float az = 0.f, ar = 0.f, ah = 0.f;
#pragma unroll 8
        for (int k = 0; k < 256; ++k) {
            float q = qs[k];
            az += bf2f(Mz[k * 256 + i]) * q;
            ar += bf2f(Mr[k * 256 + i]) * q;
            ah += bf2f(Wh[k * 256 + i]) * q;
        }
        float zz = 1.f / (1.f + expf(-(az + bzv)));
        float rr = 1.f / (1.f + expf(-(ar + brv)));
        float qo = qs[i];
        rqs[i] = rr * qo;
        __syncthreads();
        float bu = 0.f;
#pragma unroll 8
        for (int k = 0; k < 256; ++k)
            bu += bf2f(Uh[k * 256 + i]) * rqs[k];
        float h = tanhf(ah + bu + bhv);
        float qn = (1.f - zz) * qo + zz * h;
        __syncthreads();
        qs[i] = qn;
        __syncthreads();
    }
    Bt[(size_t)layer * 65536 + (size_t)j * 256 + i] = f2bf(qs[i]);
}

// ---------------- MFMA GEMM body (fp8-permuted output) ----------------
template <int ASRC>
__device__ __forceinline__ void gemm_body(int bid, int tid,
                                          const ushort* __restrict__ A,
                                          const float* __restrict__ Af,
                                          const ushort* __restrict__ Bt,
                                          unsigned char* __restrict__ C8, int M) {
    int w = tid >> 6, l = tid & 63;
    int lr = l & 15;
    int lk = l >> 4;
    int row0 = bid * 128 + w * 32;
    int ra = row0 + lr;      if (ra > M - 1) ra = M - 1;
    int rb = row0 + 16 + lr; if (rb > M - 1) rb = M - 1;
    const ushort* Ap0  = A  + (size_t)ra * 256 + lk * 8;
    const ushort* Ap1  = A  + (size_t)rb * 256 + lk * 8;
    const float*  Apf0 = Af + (size_t)ra * 256 + lk * 8;
    const float*  Apf1 = Af + (size_t)rb * 256 + lk * 8;
    const ushort* Bp   = Bt + (size_t)lr * 256 + lk * 8;

    f32x4 acc0[16] = {};
    f32x4 acc1[16] = {};
#pragma unroll
    for (int kc = 0; kc < 8; ++kc) {
        short8 a0, a1;
        if (ASRC == 0) {
            a0 = *(const short8*)(Ap0 + kc * 32);
            a1 = *(const short8*)(Ap1 + kc * 32);
        } else {
            float4 f0 = *(const float4*)(Apf0 + kc * 32);
            float4 f1 = *(const float4*)(Apf0 + kc * 32 + 4);
            float4 g0 = *(const float4*)(Apf1 + kc * 32);
            float4 g1 = *(const float4*)(Apf1 + kc * 32 + 4);
            a0[0] = (short)f2bf(f0.x); a0[1] = (short)f2bf(f0.y);
            a0[2] = (short)f2bf(f0.z); a0[3] = (short)f2bf(f0.w);
            a0[4] = (short)f2bf(f1.x); a0[5] = (short)f2bf(f1.y);
            a0[6] = (short)f2bf(f1.z); a0[7] = (short)f2bf(f1.w);
            a1[0] = (short)f2bf(g0.x); a1[1] = (short)f2bf(g0.y);
            a1[2] = (short)f2bf(g0.z); a1[3] = (short)f2bf(g0.w);
            a1[4] = (short)f2bf(g1.x); a1[5] = (short)f2bf(g1.y);
            a1[6] = (short)f2bf(g1.z); a1[7] = (short)f2bf(g1.w);
        }
#pragma unroll
        for (int nb = 0; nb < 16; ++nb) {
            short8 bf = *(const short8*)(Bp + (size_t)nb * 4096 + kc * 32);
            acc0[nb] = __builtin_amdgcn_mfma_f32_16x16x32_bf16(a0, bf, acc0[nb], 0, 0, 0);
            acc1[nb] = __builtin_amdgcn_mfma_f32_16x16x32_bf16(a1, bf, acc1[nb], 0, 0, 0);
        }
    }

    int ro = lk * 4;
#pragma unroll
    for (int q = 0; q < 4; ++q) {
        unsigned w0[4], w1[4];
#pragma unroll
        for (int t = 0; t < 4; ++t) {
            unsigned x0 = 0, x1 = 0;
#pragma unroll
            for (int u = 0; u < 4; ++u) {
                x0 |= enc8(acc0[t * 4 + u][q]) << (8 * u);
                x1 |= enc8(acc1[t * 4 + u][q]) << (8 * u);
            }
            w0[t] = x0; w1[t] = x1;
        }
        int g0 = row0 + ro + q;
        if (g0 < M)
            *(uint4*)&C8[(size_t)g0 * 256 + lr * 16] = make_uint4(w0[0], w0[1], w0[2], w0[3]);
        int g1 = row0 + 16 + ro + q;
        if (g1 < M)
            *(uint4*)&C8[(size_t)g1 * 256 + lr * 16] = make_uint4(w1[0], w1[1], w1[2], w1[3]);
    }
}

__global__ __launch_bounds__(256) void gemm_mfma(const ushort* __restrict__ A,
                                                 const ushort* __restrict__ Bt,
                                                 unsigned char* __restrict__ C8, int M) {
    gemm_body<0>(blockIdx.x, threadIdx.x, A, nullptr, Bt, C8, M);
}

// ---------------- merged: gemm0 (fp8 out) + atomic-free rank scatter (4B entries) ----
__global__ __launch_bounds__(256) void gemsca_kernel(const float* __restrict__ Af,
                                                     const ushort* __restrict__ Bt,
                                                     unsigned char* __restrict__ C8, int M,
                                                     const int* __restrict__ src,
                                                     const int* __restrict__ dst,
                                                     const float* __restrict__ val,
                                                     const int* __restrict__ base8,
                                                     const int* __restrict__ boff,
                                                     const ushort* __restrict__ rank,
                                                     unsigned* __restrict__ csr) {
    if (blockIdx.x < GB) {
        gemm_body<1>(blockIdx.x, threadIdx.x, nullptr, Af, Bt, C8, M);
        return;
    }
    int e = (blockIdx.x - GB) * 256 + threadIdx.x;
    if (e < EE) {
        int d = dst[e];
        int p = base8[8 * d + (e & 7)] + boff[d >> 8] + (int)rank[e];
        unsigned pk = (unsigned)src[e] | ((unsigned)f2bf(val[e]) << 16);
        __builtin_nontemporal_store(pk, &csr[p]);
    }
}

// ---------------- fused gemm2 + MLP head ----------------
__global__ __launch_bounds__(256) void gemm2_kernel(const ushort* __restrict__ A,
                                                    const ushort* __restrict__ Bt,
                                                    const float* __restrict__ bias,
                                                    const float* __restrict__ W2,
                                                    const float* __restrict__ b2,
                                                    float* __restrict__ out, int M) {
    __shared__ ushort Hl[128 * 264];
    int tid = threadIdx.x;
    int w = tid >> 6, l = tid & 63;
    int lr = l & 15;
    int lk = l >> 4;
    int row0 = blockIdx.x * 128 + w * 32;
    int ra = row0 + lr;      if (ra > M - 1) ra = M - 1;
    int rb = row0 + 16 + lr; if (rb > M - 1) rb = M - 1;
    const ushort* Ap0 = A + (size_t)ra * 256 + lk * 8;
    const ushort* Ap1 = A + (size_t)rb * 256 + lk * 8;
    const ushort* Bp  = Bt + (size_t)lr * 256 + lk * 8;

    f32x4 acc0[16] = {};
    f32x4 acc1[16] = {};
#pragma unroll
    for (int kc = 0; kc < 8; ++kc) {
        short8 a0 = *(const short8*)(Ap0 + kc * 32);
        short8 a1 = *(const short8*)(Ap1 + kc * 32);
#pragma unroll
        for (int nb = 0; nb < 16; ++nb) {
            short8 bf = *(const short8*)(Bp + (size_t)nb * 4096 + kc * 32);
            acc0[nb] = __builtin_amdgcn_mfma_f32_16x16x32_bf16(a0, bf, acc0[nb], 0, 0, 0);
            acc1[nb] = __builtin_amdgcn_mfma_f32_16x16x32_bf16(a1, bf, acc1[nb], 0, 0, 0);
        }
    }

    int ro = lk * 4;
    int lrow0 = w * 32;
#pragma unroll
    for (int nb = 0; nb < 16; ++nb) {
        int gc = nb * 16 + lr;
        float bb = bias[gc];
#pragma unroll
        for (int q = 0; q < 4; ++q) {
            Hl[(lrow0 + ro + q) * 264 + gc]      = f2bf(fmaxf(acc0[nb][q] + bb, 0.f));
            Hl[(lrow0 + 16 + ro + q) * 264 + gc] = f2bf(fmaxf(acc1[nb][q] + bb, 0.f));
        }
    }
    __syncthreads();

    int c = tid & 15;
    float b2v = b2[c];
#pragma unroll
    for (int it = 0; it < 8; ++it) {
        int r = it * 16 + (tid >> 4);
        int g = blockIdx.x * 128 + r;
        const ushort* hp = &Hl[r * 264];
        float acc2 = b2v;
        for (int k8 = 0; k8 < 32; ++k8) {
            short8 h8 = *(const short8*)(hp + k8 * 8);
#pragma unroll
            for (int u = 0; u < 8; ++u)
                acc2 += bf2f((ushort)h8[u]) * W2[(k8 * 8 + u) * 16 + c];
        }
        float m = acc2;
#pragma unroll
        for (int off = 1; off < 16; off <<= 1)
            m = fmaxf(m, __shfl_xor(m, off, 16));
        float ex = expf(acc2 - m);
        float s = ex;
#pragma unroll
        for (int off = 1; off < 16; off <<= 1)
            s += __shfl_xor(s, off, 16);
        if (g < M) out[(size_t)g * 16 + c] = acc2 - m - logf(s);
    }
}

// ---------------- pull aggregation (fp8 gather, hw cvt) + RReLU -> bf16 out ----------
__global__ __launch_bounds__(256) void agg_csr_kernel(const unsigned char* __restrict__ XW,
                                                      const unsigned* __restrict__ csr,
                                                      const int* __restrict__ rs,
                                                      const int* __restrict__ boff,
                                                      ushort* __restrict__ out) {
    int d = blockIdx.x * 4 + (threadIdx.x >> 6);
    if (d >= NN) return;
    int l = threadIdx.x & 63;
    int h = l >> 5;
    int il = l & 31;
    int beg = rs[d] + boff[d >> 8];
    int end = (d + 1 < NN) ? (rs[d + 1] + boff[(d + 1) >> 8]) : EE;
    float a0 = 0.f, a1 = 0.f, a2 = 0.f, a3 = 0.f;
    float a4 = 0.f, a5 = 0.f, a6 = 0.f, a7 = 0.f;
    int i = beg + h;
    for (; i + 14 < end; i += 16) {
        unsigned e[8];
        uint2 x[8];
#pragma unroll
        for (int u = 0; u < 8; ++u) e[u] = csr[i + 2 * u];
#pragma unroll
        for (int u = 0; u < 8; ++u)
            x[u] = *(const uint2*)&XW[(size_t)(e[u] & 0xffffu) * 256 + il * 8];
#pragma unroll
        for (int u = 0; u < 8; ++u) {
            float v = bf2f((ushort)(e[u] >> 16));
            f32x2 p0 = __builtin_amdgcn_cvt_pk_f32_fp8(x[u].x, false);
            f32x2 p1 = __builtin_amdgcn_cvt_pk_f32_fp8(x[u].x, true);
            f32x2 p2 = __builtin_amdgcn_cvt_pk_f32_fp8(x[u].y, false);
            f32x2 p3 = __builtin_amdgcn_cvt_pk_f32_fp8(x[u].y, true);
            a0 += v * p0.x; a1 += v * p0.y; a2 += v * p1.x; a3 += v * p1.y;
            a4 += v * p2.x; a5 += v * p2.y; a6 += v * p3.x; a7 += v * p3.y;
        }
    }
    for (; i < end; i += 2) {
        unsigned e0 = csr[i];
        float v = bf2f((ushort)(e0 >> 16));
        uint2 x0 = *(const uint2*)&XW[(size_t)(e0 & 0xffffu) * 256 + il * 8];
        f32x2 p0 = __builtin_amdgcn_cvt_pk_f32_fp8(x0.x, false);
        f32x2 p1 = __builtin_amdgcn_cvt_pk_f32_fp8(x0.x, true);
        f32x2 p2 = __builtin_amdgcn_cvt_pk_f32_fp8(x0.y, false);
        f32x2 p3 = __builtin_amdgcn_cvt_pk_f32_fp8(x0.y, true);
        a0 += v * p0.x; a1 += v * p0.y; a2 += v * p1.x; a3 += v * p1.y;
        a4 += v * p2.x; a5 += v * p2.y; a6 += v * p3.x; a7 += v * p3.y;
    }
    a0 += __shfl_xor(a0, 32); a1 += __shfl_xor(a1, 32);
    a2 += __shfl_xor(a2, 32); a3 += __shfl_xor(a3, 32);
    a4 += __shfl_xor(a4, 32); a5 += __shfl_xor(a5, 32);
    a6 += __shfl_xor(a6, 32); a7 += __shfl_xor(a7, 32);
    if (h == 0) {
        float r[8] = {a0, a1, a2, a3, a4, a5, a6, a7};
#pragma unroll
        for (int u = 0; u < 8; ++u) {
            int p = il * 8 + u;
            int c = ((p & 15) << 4) | (p >> 4);
            float v = r[u];
            v = (v >= 0.f) ? v : SLOPE_F * v;
            out[(size_t)d * D + c] = f2bf(v);
        }
    }
}

extern "C" void kernel_launch(void* const* d_in, const int* in_sizes, int n_in,
                              void* d_out, int out_size, void* d_ws, size_t ws_size,
                              hipStream_t stream) {
    const float* node_feats = (const float*)d_in[0];
    const float* edge_val   = (const float*)d_in[1];
    const float* l0_Wz = (const float*)d_in[2];
    const float* l0_Uz = (const float*)d_in[3];
    const float* l0_bz = (const float*)d_in[4];
    const float* l0_Wr = (const float*)d_in[5];
    const float* l0_Ur = (const float*)d_in[6];
    const float* l0_br = (const float*)d_in[7];
    const float* l0_Wh = (const float*)d_in[8];
    const float* l0_Uh = (const float*)d_in[9];
    const float* l0_bh = (const float*)d_in[10];
    const float* l0_Q0 = (const float*)d_in[11];
    const float* l1_Wz = (const float*)d_in[12];
    const float* l1_Uz = (const float*)d_in[13];
    const float* l1_bz = (const float*)d_in[14];
    const float* l1_Wr = (const float*)d_in[15];
    const float* l1_Ur = (const float*)d_in[16];
    const float* l1_br = (const float*)d_in[17];
    const float* l1_Wh = (const float*)d_in[18];
    const float* l1_Uh = (const float*)d_in[19];
    const float* l1_bh = (const float*)d_in[20];
    const float* l1_Q0 = (const float*)d_in[21];
    const float* W1 = (const float*)d_in[22];
    const float* b1 = (const float*)d_in[23];
    const float* W2 = (const float*)d_in[24];
    const float* b2 = (const float*)d_in[25];
    const int* e_src = (const int*)d_in[26];
    const int* e_dst = (const int*)d_in[27];
    float* out = (float*)d_out;

    // workspace layout (16B-aligned sections)
    const size_t BIG = (size_t)NN * D;   // 12.8M elements
    unsigned char* XW8 = (unsigned char*)d_ws;   // fp8 GEMM out (12.8 MB)
    ushort* H   = (ushort*)(XW8 + BIG);          // bf16 activations (h1/h2)
    ushort* Bt  = H + BIG;                       // 3 x 65536 bf16 (Qt0, Qt1, W1T)
    ushort* WB  = Bt + 3 * 65536;                // 8 mats x 65536 bf16 (transposed)
    unsigned* csr = (unsigned*)(WB + 8 * 65536); // EE (4B entries)
    int*    D8  = (int*)(csr + EE);              // 8*NN (histogram replicas)
    int*    done = D8 + 8 * NN;                  // 1 (+3 pad)
    int*    rs  = done + 4;                      // NN
    int*    base8 = rs + NN;                     // 8*NN
    int*    bsum = base8 + 8 * NN;               // 200
    int*    boff = bsum + 200;                   // 200
    ushort* rank = (ushort*)(boff + 200);        // EE

    // --- only timestep 5 contributes to the output ---
    const float* feats5 = node_feats + (size_t)5 * BIG;
    const int*   src5   = e_src + (size_t)5 * EE;
    const int*   dst5   = e_dst + (size_t)5 * EE;
    const float* val5   = edge_val + (size_t)5 * EE;

    // zero histogram replicas + done
    hipMemsetAsync(D8, 0, (8 * NN + 1) * sizeof(int), stream);

    // --- prep (144 blocks) + histogram w/ rank capture ---
    const int histblocks = (EE + 255) / 256;
    prephist_kernel<<<144 + histblocks, 256, 0, stream>>>(
        l0_Wz, l0_Uz, l0_Wr, l0_Ur, l0_Wh, l0_Uh,
        l1_Wz, l1_Uz, l1_Wr, l1_Ur, l1_Wh, l1_Uh,
        W1, WB, Bt + 2 * 65536, dst5, D8, rank);

    // --- GRU (512 blocks) + hierarchical scan over replicas (196 blocks) ---
    gruscan_kernel<<<512 + NCH, 256, 0, stream>>>(WB, l0_bz, l0_br, l0_bh, l0_Q0,
                                                  l1_bz, l1_br, l1_bh, l1_Q0, Bt,
                                                  D8, rs, base8, bsum, boff, done);

    // --- gemm0 (A = fp32 feats, B = Qt0, out fp8-permuted) + rank scatter ---
    gemsca_kernel<<<GB + histblocks, 256, 0, stream>>>(feats5, Bt + 0 * 65536, XW8, NN,
                                                       src5, dst5, val5, base8, boff,
                                                       rank, csr);

    const int ablocks = (NN + 3) / 4;           // 12500

    // agg0: fp8 gather -> bf16 h1
    agg_csr_kernel<<<ablocks, 256, 0, stream>>>(XW8, csr, rs, boff, H);

    // gemm1: h1 @ Qt1 -> fp8-permuted
    gemm_mfma<<<GB, 256, 0, stream>>>(H, Bt + 1 * 65536, XW8, NN);

    // agg1: fp8 gather -> bf16 h2
    agg_csr_kernel<<<ablocks, 256, 0, stream>>>(XW8, csr, rs, boff, H);

    // gemm2 + bias/relu + MLP head + log_softmax, fused
    gemm2_kernel<<<GB, 256, 0, stream>>>(H, Bt + 2 * 65536, b1, W2, b2, out, NN);
}